// Round 12
// baseline (247.852 us; speedup 1.0000x reference)
//
#include <hip/hip_runtime.h>
#include <hip/hip_bf16.h>
#include <stdint.h>

// Problem constants
#define NB 2
#define NT 4096
#define NC 768
#define NHEAD 12
#define HS 64
#define MTOK (NB * NT)      // 8192
#define C3 (3 * NC)         // 2304
#define CQK (2 * NC)        // qkvb row stride: Q,K only (V lives in vTb)

typedef __bf16 bf16x8 __attribute__((ext_vector_type(8)));
typedef float f32x4 __attribute__((ext_vector_type(4)));
typedef float f32x16 __attribute__((ext_vector_type(16)));

#define KSCALE_LOG2E 0.18033688011f   // (1/sqrt(64)) * log2(e)

__device__ __forceinline__ unsigned short f2bf(float f) {  // RNE
  union { float f; uint32_t u; } v; v.f = f;
  uint32_t r = v.u + 0x7fffu + ((v.u >> 16) & 1u);
  return (unsigned short)(r >> 16);
}
__device__ __forceinline__ unsigned short bft(float f) {   // truncate
  return (unsigned short)(__builtin_bit_cast(unsigned int, f) >> 16);
}
// pack two floats as truncated bf16 pair via v_perm_b32: D = [a.hi16 | b.hi16<<16]
__device__ __forceinline__ uint32_t pack_bf2(float a, float b) {
  return __builtin_amdgcn_perm(__builtin_bit_cast(uint32_t, a),
                               __builtin_bit_cast(uint32_t, b), 0x03020706u);
}

// async global->LDS, 16B per lane: lane i lands at ldsbase + i*16B.
__device__ __forceinline__ void gload_lds16(const unsigned short* g, unsigned short* ldsbase) {
  __builtin_amdgcn_global_load_lds(
      (const __attribute__((address_space(1))) unsigned int*)g,
      (__attribute__((address_space(3))) unsigned int*)ldsbase, 16, 0, 0);
}

__device__ __forceinline__ f32x4 mfma16(bf16x8 a, bf16x8 b, f32x4 c) {
  return __builtin_amdgcn_mfma_f32_16x16x32_bf16(a, b, c, 0, 0, 0);
}
__device__ __forceinline__ f32x16 mfma32(bf16x8 a, bf16x8 b, f32x16 c) {
  return __builtin_amdgcn_mfma_f32_32x32x16_bf16(a, b, c, 0, 0, 0);
}

// ---------------- prep: coalesced LDS-tiled transposes + x cast ----------------
__global__ __launch_bounds__(256) void prep(
    const float* __restrict__ x, const float* __restrict__ wa, const float* __restrict__ wp,
    unsigned short* __restrict__ xb, unsigned short* __restrict__ waT,
    unsigned short* __restrict__ wpT) {
  const int bx = blockIdx.x;
  if (bx < 576) {
    __shared__ float tile[64][65];
    const float* src; unsigned short* dst;
    int srcN, dstN, k0, n0, qscale;
    if (bx < 432) {
      src = wa; dst = waT; srcN = C3; dstN = NC; qscale = 1;
      k0 = (bx / 36) * 64; n0 = (bx % 36) * 64;
    } else {
      const int t = bx - 432;
      src = wp; dst = wpT; srcN = NC; dstN = NC; qscale = 0;
      k0 = (t / 12) * 64; n0 = (t % 12) * 64;
    }
    const int tr = threadIdx.x >> 4;        // 0..15
    const int tc = (threadIdx.x & 15) * 4;  // 0,4,..,60
#pragma unroll
    for (int p = 0; p < 4; ++p) {
      const int r = p * 16 + tr;
      const float4 v = *reinterpret_cast<const float4*>(src + (size_t)(k0 + r) * srcN + n0 + tc);
      tile[r][tc + 0] = v.x; tile[r][tc + 1] = v.y;
      tile[r][tc + 2] = v.z; tile[r][tc + 3] = v.w;
    }
    __syncthreads();
#pragma unroll
    for (int p = 0; p < 4; ++p) {
      const int n = p * 16 + tr;   // output row = source column n0+n
      const float sc = (qscale && (n0 + n) < NC) ? KSCALE_LOG2E : 1.0f;
      ushort4 o;
      o.x = f2bf(tile[tc + 0][n] * sc); o.y = f2bf(tile[tc + 1][n] * sc);
      o.z = f2bf(tile[tc + 2][n] * sc); o.w = f2bf(tile[tc + 3][n] * sc);
      *reinterpret_cast<ushort4*>(dst + (size_t)(n0 + n) * dstN + k0 + tc) = o;
    }
  } else {
    const int gid = (bx - 576) * 256 + threadIdx.x;   // < MTOK*NC/4
    const float4 v = reinterpret_cast<const float4*>(x)[gid];
    ushort4 o;
    o.x = f2bf(v.x); o.y = f2bf(v.y); o.z = f2bf(v.z); o.w = f2bf(v.w);
    reinterpret_cast<ushort4*>(xb)[gid] = o;
  }
}

// ---------------- GEMM 128x128: C[M,N] = A[M,K] @ Bt[N,K]^T ----------------
// 1D grid with XCD-chunked bijective swizzle: w = (bid&7)*(nwg/8) + bid/8,
// cx = w % nx (fastest) -> each XCD processes complete row panels
// consecutively: A panel fetched once chip-wide, B stays L2-resident per XCD.
// ldc = output row stride. OUT_BF16=1 (gemm1): blocks with col0 >= 2*NC hold
// the V tile -> transpose in-block via smem and write straight to vT
// [B*NH][HS][T]; Q/K blocks write bf16 rows at stride ldc.
template <int OUT_BF16>
__global__ __launch_bounds__(256) void gemm128(
    const unsigned short* __restrict__ A,   // [M][K]
    const unsigned short* __restrict__ Bt,  // [N][K]
    void* __restrict__ Cout,
    unsigned short* __restrict__ vT,        // used only by OUT_BF16 V-blocks
    int M, int N, int K, int ldc, int nx) {
  __shared__ unsigned short smem[2 * 128 * 64];
  unsigned short* As = smem;
  unsigned short* Bs = smem + 128 * 64;

  const int tid = threadIdx.x;
  const int wave = tid >> 6;
  const int lane = tid & 63;
  const int li = lane & 15;
  const int lq = lane >> 4;
  const int wm = wave & 1;
  const int wn = wave >> 1;

  const int bid = (int)blockIdx.x;
  const int nwg = (int)gridDim.x;           // multiple of 8
  const int w = (bid & 7) * (nwg >> 3) + (bid >> 3);
  const int cx = w % nx;
  const int cy = w / nx;
  const int row0 = cy * 128;
  const int col0 = cx * 128;

  const int crow = lane >> 3;
  const int cchunk = ((lane & 7) ^ crow) * 8;

  f32x4 acc[4][4] = {};

  for (int k0 = 0; k0 < K; k0 += 64) {
#pragma unroll
    for (int i = 0; i < 4; ++i) {
      const int R = wave * 32 + i * 8;
      gload_lds16(A + (size_t)(row0 + R + crow) * K + k0 + cchunk, &As[R * 64]);
      gload_lds16(Bt + (size_t)(col0 + R + crow) * K + k0 + cchunk, &Bs[R * 64]);
    }
    __syncthreads();

#pragma unroll
    for (int ks = 0; ks < 2; ++ks) {
      bf16x8 af[4], bf[4];
#pragma unroll
      for (int f = 0; f < 4; ++f) {
        const int arow = wm * 64 + f * 16 + li;
        af[f] = *reinterpret_cast<const bf16x8*>(&As[arow * 64 + (((ks * 4 + lq) ^ (li & 7)) << 3)]);
        const int brow = wn * 64 + f * 16 + li;
        bf[f] = *reinterpret_cast<const bf16x8*>(&Bs[brow * 64 + (((ks * 4 + lq) ^ (li & 7)) << 3)]);
      }
#pragma unroll
      for (int fa = 0; fa < 4; ++fa)
#pragma unroll
        for (int fb = 0; fb < 4; ++fb)
          acc[fa][fb] = mfma16(af[fa], bf[fb], acc[fa][fb]);
    }
    __syncthreads();   // also protects smem reuse in the fused epilogue
  }

  if (OUT_BF16) {
    if (col0 >= 2 * NC) {
      // ---- fused V transpose: acc -> smem[c][t] -> vT[bh][d][t] ----
      const int b = row0 >> 12;            // row0 / NT
      const int t0r = row0 & (NT - 1);
      const int h0 = (col0 - 2 * NC) >> 6;
      // write phase: value at (c = head-col, t = token) with 16B-chunk XOR swizzle
#pragma unroll
      for (int fa = 0; fa < 4; ++fa) {
#pragma unroll
        for (int fb = 0; fb < 4; ++fb) {
          const int cc = wn * 64 + fb * 16 + li;
#pragma unroll
          for (int r = 0; r < 4; ++r) {
            const int tt = wm * 64 + fa * 16 + lq * 4 + r;
            const int slot = cc * 16 + ((tt >> 3) ^ (cc & 15));
            smem[slot * 8 + (tt & 7)] = f2bf(acc[fa][fb][r]);
          }
        }
      }
      __syncthreads();
      // read phase: 16 lanes cover one c-row's 16 chunks -> 256B coalesced stores
      const int ch = tid & 15;
#pragma unroll
      for (int j = 0; j < 8; ++j) {
        const int cc = (tid >> 4) + 16 * j;
        const uint4 v = *reinterpret_cast<const uint4*>(
            smem + (size_t)(cc * 16 + (ch ^ (cc & 15))) * 8);
        const int bh = b * NHEAD + h0 + (cc >> 6);
        const int d = cc & 63;
        *reinterpret_cast<uint4*>(vT + (size_t)bh * HS * NT + (size_t)d * NT + t0r + ch * 8) = v;
      }
    } else {
      unsigned short* Cb = (unsigned short*)Cout;
#pragma unroll
      for (int fa = 0; fa < 4; ++fa) {
        const int gr = row0 + wm * 64 + fa * 16 + lq * 4;
#pragma unroll
        for (int fb = 0; fb < 4; ++fb) {
          const int gc = col0 + wn * 64 + fb * 16 + li;
#pragma unroll
          for (int r = 0; r < 4; ++r)
            Cb[(size_t)(gr + r) * ldc + gc] = f2bf(acc[fa][fb][r]);
        }
      }
    }
  } else {
    float* Cf = (float*)Cout;
#pragma unroll
    for (int fa = 0; fa < 4; ++fa) {
      const int gr = row0 + wm * 64 + fa * 16 + lq * 4;
#pragma unroll
      for (int fb = 0; fb < 4; ++fb) {
        const int gc = col0 + wn * 64 + fb * 16 + li;
#pragma unroll
        for (int r = 0; r < 4; ++r)
          Cf[(size_t)(gr + r) * ldc + gc] = acc[fa][fb][r];
      }
    }
  }
}

// ---------------- Flash attention: explicit 33-tile paired blocks ----------------
// Total tile-work = 24 heads x 1056 = 25344 = 768 blocks x 33 EXACTLY.
// One block = TWO segments on the same (b,h):
//   seg0: part0 (diagonal half) of q-tile qia        -> size qia+1 tiles -> slot A
//   seg1: part1 (lower half)   of q-tile 31-qia      -> size 32-qia tiles -> slot B
// Every block is exactly 33 tiles -> 768 equal blocks = exactly 3/CU (48KB LDS
// cap), zero dispatch tail, no scheduler-dependent pairing. Same head both
// segments -> K/V L2 locality preserved. Slot B storage = d_out (dead until
// gemm2, which runs after finalize). No atomics, no memset: every slot row
// written exactly once.
// Inner tile body unchanged from R10: 3-deep LDS ring, counted vmcnt(4), one
// s_barrier/tile, swapped 32x32 QK^T (zero-C first MFMA), compile-time-split
// causal mask, v_perm packing, permlane P rebuild, l row-sums on MFMA pipe.
// qkv buffer is [B][T][2C] (Q,K only; V lives in vTb).

__global__ __launch_bounds__(256) void attn(
    const unsigned short* __restrict__ qkv,   // [B][T][2C]
    const unsigned short* __restrict__ vT,    // [B*NH][HS][T]
    float* __restrict__ OpartA,               // [MTOK][NC] fp32 slot A
    float* __restrict__ OpartB,               // [MTOK][NC] fp32 slot B (= d_out scratch)
    float* __restrict__ laccA,                // [B*NH][NT]  fp32 slot A
    float* __restrict__ laccB) {              // [B*NH][NT]  fp32 slot B
  __shared__ unsigned short Ks[3][64 * 64];
  __shared__ unsigned short Vts[3][64 * 64];

  const int tid = threadIdx.x;
  const int wave = tid >> 6;
  const int lane = tid & 63;
  const int l31 = lane & 31;
  const int lh = lane >> 5;
  const int sw = l31 & 7;                     // XOR-swizzle key for frag reads

  // ---- block decode: 768 = 8 XCD * 3 groups * 32 qia ----
  const int bid = (int)blockIdx.x;
  const int xcd = bid & 7;
  const int wl = bid >> 3;                    // 0..95
  const int grp = xcd * 3 + wl % 3;           // b*12+h
  const int qia = 31 - wl / 3;                // seg0 q-tile (31..0)
  const int b = grp / 12;
  const int h = grp - b * 12;
  const int bh = grp;

  const size_t baseQ = (size_t)b * NT * CQK + (size_t)h * HS;
  const size_t baseK = baseQ + NC;
  const unsigned short* kq = qkv + baseK;
  const unsigned short* vbase = vT + (size_t)bh * HS * NT;

  // all-ones B fragment for l row-sums on the MFMA pipe
  bf16x8 vones;
#pragma unroll
  for (int i = 0; i < 8; ++i) vones[i] = (__bf16)1.0f;
  const f32x16 zf = {};            // persistent zero C-operand

  // ---- gload staging geometry: per wave, 2 calls x 8 rows for K and V ----
  // DMA writes linear (wave-uniform LDS base + lane*16B); the XOR swizzle is
  // applied on the per-lane GLOBAL address instead: LDS[R][c] = G[R][c^(R&7)].
  const int grow = lane >> 3;               // row within 8-row group
  const int gch = (lane & 7) ^ grow;        // pre-swizzled 16B chunk
  const int wr0 = wave * 8;                 // uniform row bases
  const int wr1 = wave * 8 + 32;

#define STAGE(TAU, BUFI)                                                        \
  do {                                                                          \
    const int t0s_ = (TAU) * 64;                                                \
    gload_lds16(kq + (size_t)(t0s_ + wr0 + grow) * CQK + gch * 8,               \
                &Ks[BUFI][wr0 * 64]);                                           \
    gload_lds16(kq + (size_t)(t0s_ + wr1 + grow) * CQK + gch * 8,               \
                &Ks[BUFI][wr1 * 64]);                                           \
    gload_lds16(vbase + (size_t)(wr0 + grow) * NT + t0s_ + gch * 8,             \
                &Vts[BUFI][wr0 * 64]);                                          \
    gload_lds16(vbase + (size_t)(wr1 + grow) * NT + t0s_ + gch * 8,             \
                &Vts[BUFI][wr1 * 64]);                                          \
  } while (0)

// exp + pack + permlane-swap one 32-k block (16 S^T regs) into pa[2*KBLK+s].
// DOMASK is a LITERAL 0/1 (selected by a wave-uniform branch at the call site).
#define EXP_PACK(ST, KBLK, DOMASK)                                             \
  do {                                                                         \
    const int kb_ = t0 + (KBLK) * 32 + 4 * lh;                                 \
    float p_[16];                                                              \
    _Pragma("unroll") for (int r = 0; r < 16; ++r) {                           \
      float v_ = (ST)[r];                                                      \
      if (DOMASK) {                                                            \
        const int kt_ = kb_ + (r & 3) + 8 * (r >> 2);                          \
        if (kt_ > qtok) v_ = -INFINITY;                                        \
      }                                                                        \
      p_[r] = __builtin_amdgcn_exp2f(v_);                                      \
    }                                                                          \
    _Pragma("unroll") for (int s = 0; s < 2; ++s) {                            \
      uint32_t a_ = pack_bf2(p_[8 * s + 0], p_[8 * s + 1]);                    \
      uint32_t b_ = pack_bf2(p_[8 * s + 2], p_[8 * s + 3]);                    \
      uint32_t c_ = pack_bf2(p_[8 * s + 4], p_[8 * s + 5]);                    \
      uint32_t d_ = pack_bf2(p_[8 * s + 6], p_[8 * s + 7]);                    \
      asm("v_permlane32_swap_b32 %0, %1" : "+v"(a_), "+v"(c_));                \
      asm("v_permlane32_swap_b32 %0, %1" : "+v"(b_), "+v"(d_));                \
      union { uint32_t u[4]; bf16x8 v8; } pu_;                                 \
      pu_.u[0] = a_; pu_.u[1] = b_; pu_.u[2] = c_; pu_.u[3] = d_;              \
      pa[2 * (KBLK) + s] = pu_.v8;                                             \
    }                                                                          \
  } while (0)

// one PV k-step (16 k-tokens): l += P.1 ; O += P V  (V B-frag rows = d)
#define PV_STEP(KS)                                                            \
  do {                                                                         \
    const int off_ = ((((KS) * 2 + lh) ^ sw) << 3);                            \
    const bf16x8 bv0_ =                                                        \
        *reinterpret_cast<const bf16x8*>(Vc + (size_t)l31 * 64 + off_);        \
    const bf16x8 bv1_ =                                                        \
        *reinterpret_cast<const bf16x8*>(Vc + (size_t)(32 + l31) * 64 + off_); \
    la = mfma32(pa[KS], vones, la);                                            \
    o0 = mfma32(pa[KS], bv0_, o0);                                             \
    o1 = mfma32(pa[KS], bv1_, o1);                                             \
  } while (0)

  for (int seg = 0; seg < 2; ++seg) {
    const int part = seg;                     // 0: slot A, 1: slot B
    const int qi = part ? (31 - qia) : qia;
    const int q0 = qi * 128;
    const int tauS = part ? 0 : (qi + 1);
    const int tauE = part ? (qi + 1) : (2 * qi + 2);

    const int qw = q0 + wave * 32;            // wave's first q row
    const int qtok = qw + l31;                // this lane's q token

    // Q B-fragments (pre-scaled via waT): lane holds Q[q=qw+l31][ks*16+lh*8..+7]
    bf16x8 bq[4];
#pragma unroll
    for (int ks = 0; ks < 4; ++ks)
      bq[ks] = *reinterpret_cast<const bf16x8*>(
          qkv + baseQ + (size_t)(qw + l31) * CQK + ks * 16 + lh * 8);

    f32x16 o0 = {}, o1 = {}, la = {};

    if (seg) __syncthreads();   // all waves done reading seg0's LDS buffers

    // prologue: 2 tiles in flight (single-tile segments stage one extra tile;
    // the staged index never exceeds 63, so reads stay in-bounds)
    STAGE(tauS, 0);
    STAGE(tauS + 1, 1);

    int cur = 0;
    for (int tau = tauS; tau < tauE; ++tau) {
      const int t0 = tau * 64;
      // counted drain: tile tau's 4 loads landed; tau+1's stay in flight.
      if (tau + 1 < tauE) asm volatile("s_waitcnt vmcnt(4)" ::: "memory");
      else                asm volatile("s_waitcnt vmcnt(0)" ::: "memory");
      __builtin_amdgcn_s_barrier();          // publish buf[cur] to all waves
      __builtin_amdgcn_sched_barrier(0);     // no hoisting across the barrier
      if (tau + 2 < tauE) {
        int nb = cur + 2; if (nb >= 3) nb -= 3;   // overwrites buf read at tau-1
        STAGE(tau + 2, nb);
      }

      const unsigned short* Kc = Ks[cur];
      const unsigned short* Vc = Vts[cur];

      if (t0 <= qw + 31) {                 // wave has live q-rows in this tile
        const bool act1 = (t0 + 32 <= qw + 31);   // k-block 1 live?
        const bool m0 = (t0 + 31 > qw);           // k-block 0 needs masking?
        const bool m1 = (t0 + 63 > qw);           // k-block 1 needs masking?

        // ---- S^T = K Q^T: A = K rows (k-tokens), B = Q cols ----
        f32x16 st0, st1;
        __builtin_amdgcn_s_setprio(1);
        {
          const bf16x8 ka0 = *reinterpret_cast<const bf16x8*>(
              Kc + (size_t)l31 * 64 + ((lh ^ sw) << 3));
          st0 = mfma32(ka0, bq[0], zf);
        }
#pragma unroll
        for (int ks = 1; ks < 4; ++ks) {
          const bf16x8 ka = *reinterpret_cast<const bf16x8*>(
              Kc + (size_t)l31 * 64 + (((ks * 2 + lh) ^ sw) << 3));
          st0 = mfma32(ka, bq[ks], st0);
        }
        if (act1) {
          {
            const bf16x8 ka0 = *reinterpret_cast<const bf16x8*>(
                Kc + (size_t)(32 + l31) * 64 + ((lh ^ sw) << 3));
            st1 = mfma32(ka0, bq[0], zf);
          }
#pragma unroll
          for (int ks = 1; ks < 4; ++ks) {
            const bf16x8 ka = *reinterpret_cast<const bf16x8*>(
                Kc + (size_t)(32 + l31) * 64 + (((ks * 2 + lh) ^ sw) << 3));
            st1 = mfma32(ka, bq[ks], st1);
          }
        }
        __builtin_amdgcn_s_setprio(0);

        // ---- exp + pack + swap -> pa[4]; mask code only on diagonal tiles ----
        bf16x8 pa[4];
        if (m0) EXP_PACK(st0, 0, 1); else EXP_PACK(st0, 0, 0);
        if (act1) {
          if (m1) EXP_PACK(st1, 1, 1); else EXP_PACK(st1, 1, 0);
        }

        // ---- O += P V ; l += P . ones (MFMA pipe) ----
        __builtin_amdgcn_s_setprio(1);
        PV_STEP(0); PV_STEP(1);
        if (act1) { PV_STEP(2); PV_STEP(3); }
        __builtin_amdgcn_s_setprio(0);
      }
      ++cur; if (cur == 3) cur = 0;
    }

    // ---- epilogue: deterministic slot store (no atomics) ----
    // o0/o1 C-layout: col = l31 (d), reg r -> q = qw + (r&3)+8*(r>>2)+4*lh.
    // la[r] = row-sum, uniform across l31.
    float* slotO = part ? OpartB : OpartA;
    float* lrow = (part ? laccB : laccA) + (size_t)bh * NT;
#pragma unroll
    for (int r = 0; r < 16; ++r) {
      const int q = qw + (r & 3) + 8 * (r >> 2) + 4 * lh;
      if (l31 == 0) lrow[q] = la[r];
      float* orow = slotO + ((size_t)b * NT + q) * NC + h * HS;
      orow[l31] = o0[r];
      orow[32 + l31] = o1[r];
    }
  }
#undef STAGE
#undef EXP_PACK
#undef PV_STEP
}

// ---------------- finalize: merge slots, aob = bf16((OA+OB)/(lA+lB)), all rows ----
__global__ __launch_bounds__(256) void finalize(
    const float* __restrict__ OpartA, const float* __restrict__ OpartB,
    const float* __restrict__ laccA, const float* __restrict__ laccB,
    unsigned short* __restrict__ aob) {
  const int idx4 = (blockIdx.x * 256 + threadIdx.x);
  if (idx4 >= MTOK * NC / 4) return;
  const int idx = idx4 * 4;
  const int row = idx / NC;           // b*NT + t
  const int cc = idx - row * NC;
  const int b = row >> 12;            // NT = 4096
  const int t = row & (NT - 1);
  const int h = cc >> 6;
  const size_t lofs = (size_t)(b * NHEAD + h) * NT + t;
  const float inv = 1.0f / (laccA[lofs] + laccB[lofs]);
  const float4 v0 = *reinterpret_cast<const float4*>(OpartA + (size_t)idx);
  const float4 v1 = *reinterpret_cast<const float4*>(OpartB + (size_t)idx);
  ushort4 o;
  o.x = bft((v0.x + v1.x) * inv); o.y = bft((v0.y + v1.y) * inv);
  o.z = bft((v0.z + v1.z) * inv); o.w = bft((v0.w + v1.w) * inv);
  reinterpret_cast<ushort4*>(aob)[idx4] = o;
}

// ---------------- launch ----------------
extern "C" void kernel_launch(void* const* d_in, const int* in_sizes, int n_in,
                              void* d_out, int out_size, void* d_ws, size_t ws_size,
                              hipStream_t stream) {
  const float* x = (const float*)d_in[0];       // [B,T,C]
  const float* w_attn = (const float*)d_in[1];  // [C, 3C]
  const float* w_proj = (const float*)d_in[2];  // [C, C]
  float* outp = (float*)d_out;

  // ws layout (total ~77.5 MB, safely below the ~89.6 MB proven budget):
  //   OpartA [MTOK][NC] f32  (aliases xb/waT, which die after gemm1)
  //   laccA  [B*NH][NT] f32
  //   laccB  [B*NH][NT] f32
  //   qkvb   [MTOK][2NC] bf16  (Q,K only — V written straight to vTb)
  //   aob    [MTOK][NC] bf16
  //   vTb    [B*NH][HS][T] bf16
  //   wpT    [NC][NC] bf16
  // OpartB = d_out scratch (dead until gemm2, which runs after finalize).
  char* w = (char*)d_ws;
  float* OpartA = (float*)w;
  unsigned short* xb = (unsigned short*)w;                       // aliases OpartA (pre-attn)
  unsigned short* waT = xb + (size_t)MTOK * NC;                  // aliases OpartA tail
  float* laccA = OpartA + (size_t)MTOK * NC;
  float* laccB = laccA + (size_t)NB * NHEAD * NT;
  unsigned short* qkvb = (unsigned short*)(laccB + (size_t)NB * NHEAD * NT);
  unsigned short* aob  = qkvb + (size_t)MTOK * CQK;              // [MTOK][NC] bf16
  unsigned short* vTb  = aob + (size_t)MTOK * NC;                // [B*NH][HS][T]
  unsigned short* wpT  = vTb + (size_t)MTOK * NC;                // [NC][NC] bf16

  // prep: 576 transpose tiles + x-cast blocks
  prep<<<576 + MTOK * NC / 4 / 256, 256, 0, stream>>>(x, w_attn, w_proj, xb, waT, wpT);

  // qkv = x @ w_attn (Q rows of waT pre-scaled); V blocks write vTb directly;
  // Q/K rows land in qkvb at stride 2NC. 1152 = 8*144 blocks, XCD-chunked.
  gemm128<1><<<1152, 256, 0, stream>>>(
      xb, waT, qkvb, vTb, MTOK, C3, NC, CQK, C3 / 128);

  // attention: 768 explicit 33-tile paired blocks, dual deterministic slots
  attn<<<768, 256, 0, stream>>>(qkvb, vTb, OpartA, outp, laccA, laccB);

  // merge slots + normalize all rows -> bf16 aob
  finalize<<<(MTOK * NC / 4 + 255) / 256, 256, 0, stream>>>(OpartA, outp, laccA, laccB, aob);

  // out = att_out @ w_proj -> fp32 d_out. 384 = 8*48 blocks, XCD-chunked.
  gemm128<0><<<384, 256, 0, stream>>>(
      aob, wpT, outp, nullptr, MTOK, NC, NC, NC, NC / 128);
}

// Round 13
// 217.986 us; speedup vs baseline: 1.1370x; 1.1370x over previous
//
#include <hip/hip_runtime.h>
#include <hip/hip_bf16.h>
#include <stdint.h>

// Problem constants
#define NB 2
#define NT 4096
#define NC 768
#define NHEAD 12
#define HS 64
#define MTOK (NB * NT)      // 8192
#define C3 (3 * NC)         // 2304
#define CQK (2 * NC)        // qkvb row stride: Q,K only (V lives in vTb)

typedef __bf16 bf16x8 __attribute__((ext_vector_type(8)));
typedef float f32x4 __attribute__((ext_vector_type(4)));
typedef float f32x16 __attribute__((ext_vector_type(16)));

#define KSCALE_LOG2E 0.18033688011f   // (1/sqrt(64)) * log2(e)

__device__ __forceinline__ unsigned short f2bf(float f) {  // RNE
  union { float f; uint32_t u; } v; v.f = f;
  uint32_t r = v.u + 0x7fffu + ((v.u >> 16) & 1u);
  return (unsigned short)(r >> 16);
}
__device__ __forceinline__ unsigned short bft(float f) {   // truncate
  return (unsigned short)(__builtin_bit_cast(unsigned int, f) >> 16);
}
// pack two floats as truncated bf16 pair via v_perm_b32: D = [a.hi16 | b.hi16<<16]
__device__ __forceinline__ uint32_t pack_bf2(float a, float b) {
  return __builtin_amdgcn_perm(__builtin_bit_cast(uint32_t, a),
                               __builtin_bit_cast(uint32_t, b), 0x03020706u);
}

// async global->LDS, 16B per lane: lane i lands at ldsbase + i*16B.
__device__ __forceinline__ void gload_lds16(const unsigned short* g, unsigned short* ldsbase) {
  __builtin_amdgcn_global_load_lds(
      (const __attribute__((address_space(1))) unsigned int*)g,
      (__attribute__((address_space(3))) unsigned int*)ldsbase, 16, 0, 0);
}

__device__ __forceinline__ f32x4 mfma16(bf16x8 a, bf16x8 b, f32x4 c) {
  return __builtin_amdgcn_mfma_f32_16x16x32_bf16(a, b, c, 0, 0, 0);
}
__device__ __forceinline__ f32x16 mfma32(bf16x8 a, bf16x8 b, f32x16 c) {
  return __builtin_amdgcn_mfma_f32_32x32x16_bf16(a, b, c, 0, 0, 0);
}

// ---------------- prep: coalesced LDS-tiled transposes + x cast ----------------
__global__ __launch_bounds__(256) void prep(
    const float* __restrict__ x, const float* __restrict__ wa, const float* __restrict__ wp,
    unsigned short* __restrict__ xb, unsigned short* __restrict__ waT,
    unsigned short* __restrict__ wpT) {
  const int bx = blockIdx.x;
  if (bx < 576) {
    __shared__ float tile[64][65];
    const float* src; unsigned short* dst;
    int srcN, dstN, k0, n0, qscale;
    if (bx < 432) {
      src = wa; dst = waT; srcN = C3; dstN = NC; qscale = 1;
      k0 = (bx / 36) * 64; n0 = (bx % 36) * 64;
    } else {
      const int t = bx - 432;
      src = wp; dst = wpT; srcN = NC; dstN = NC; qscale = 0;
      k0 = (t / 12) * 64; n0 = (t % 12) * 64;
    }
    const int tr = threadIdx.x >> 4;        // 0..15
    const int tc = (threadIdx.x & 15) * 4;  // 0,4,..,60
#pragma unroll
    for (int p = 0; p < 4; ++p) {
      const int r = p * 16 + tr;
      const float4 v = *reinterpret_cast<const float4*>(src + (size_t)(k0 + r) * srcN + n0 + tc);
      tile[r][tc + 0] = v.x; tile[r][tc + 1] = v.y;
      tile[r][tc + 2] = v.z; tile[r][tc + 3] = v.w;
    }
    __syncthreads();
#pragma unroll
    for (int p = 0; p < 4; ++p) {
      const int n = p * 16 + tr;   // output row = source column n0+n
      const float sc = (qscale && (n0 + n) < NC) ? KSCALE_LOG2E : 1.0f;
      ushort4 o;
      o.x = f2bf(tile[tc + 0][n] * sc); o.y = f2bf(tile[tc + 1][n] * sc);
      o.z = f2bf(tile[tc + 2][n] * sc); o.w = f2bf(tile[tc + 3][n] * sc);
      *reinterpret_cast<ushort4*>(dst + (size_t)(n0 + n) * dstN + k0 + tc) = o;
    }
  } else {
    const int gid = (bx - 576) * 256 + threadIdx.x;   // < MTOK*NC/4
    const float4 v = reinterpret_cast<const float4*>(x)[gid];
    ushort4 o;
    o.x = f2bf(v.x); o.y = f2bf(v.y); o.z = f2bf(v.z); o.w = f2bf(v.w);
    reinterpret_cast<ushort4*>(xb)[gid] = o;
  }
}

// ---------------- GEMM 128x128: C[M,N] = A[M,K] @ Bt[N,K]^T ----------------
// 1D grid with XCD-chunked bijective swizzle: w = (bid&7)*(nwg/8) + bid/8,
// cx = w % nx (fastest) -> each XCD processes complete row panels
// consecutively: A panel fetched once chip-wide, B stays L2-resident per XCD.
// ldc = output row stride. OUT_BF16=1 (gemm1): blocks with col0 >= 2*NC hold
// the V tile -> transpose in-block via smem and write straight to vT
// [B*NH][HS][T]; Q/K blocks write bf16 rows at stride ldc.
template <int OUT_BF16>
__global__ __launch_bounds__(256) void gemm128(
    const unsigned short* __restrict__ A,   // [M][K]
    const unsigned short* __restrict__ Bt,  // [N][K]
    void* __restrict__ Cout,
    unsigned short* __restrict__ vT,        // used only by OUT_BF16 V-blocks
    int M, int N, int K, int ldc, int nx) {
  __shared__ unsigned short smem[2 * 128 * 64];
  unsigned short* As = smem;
  unsigned short* Bs = smem + 128 * 64;

  const int tid = threadIdx.x;
  const int wave = tid >> 6;
  const int lane = tid & 63;
  const int li = lane & 15;
  const int lq = lane >> 4;
  const int wm = wave & 1;
  const int wn = wave >> 1;

  const int bid = (int)blockIdx.x;
  const int nwg = (int)gridDim.x;           // multiple of 8
  const int w = (bid & 7) * (nwg >> 3) + (bid >> 3);
  const int cx = w % nx;
  const int cy = w / nx;
  const int row0 = cy * 128;
  const int col0 = cx * 128;

  const int crow = lane >> 3;
  const int cchunk = ((lane & 7) ^ crow) * 8;

  f32x4 acc[4][4] = {};

  for (int k0 = 0; k0 < K; k0 += 64) {
#pragma unroll
    for (int i = 0; i < 4; ++i) {
      const int R = wave * 32 + i * 8;
      gload_lds16(A + (size_t)(row0 + R + crow) * K + k0 + cchunk, &As[R * 64]);
      gload_lds16(Bt + (size_t)(col0 + R + crow) * K + k0 + cchunk, &Bs[R * 64]);
    }
    __syncthreads();

#pragma unroll
    for (int ks = 0; ks < 2; ++ks) {
      bf16x8 af[4], bf[4];
#pragma unroll
      for (int f = 0; f < 4; ++f) {
        const int arow = wm * 64 + f * 16 + li;
        af[f] = *reinterpret_cast<const bf16x8*>(&As[arow * 64 + (((ks * 4 + lq) ^ (li & 7)) << 3)]);
        const int brow = wn * 64 + f * 16 + li;
        bf[f] = *reinterpret_cast<const bf16x8*>(&Bs[brow * 64 + (((ks * 4 + lq) ^ (li & 7)) << 3)]);
      }
#pragma unroll
      for (int fa = 0; fa < 4; ++fa)
#pragma unroll
        for (int fb = 0; fb < 4; ++fb)
          acc[fa][fb] = mfma16(af[fa], bf[fb], acc[fa][fb]);
    }
    __syncthreads();   // also protects smem reuse in the fused epilogue
  }

  if (OUT_BF16) {
    if (col0 >= 2 * NC) {
      // ---- fused V transpose: acc -> smem[c][t] -> vT[bh][d][t] ----
      const int b = row0 >> 12;            // row0 / NT
      const int t0r = row0 & (NT - 1);
      const int h0 = (col0 - 2 * NC) >> 6;
      // write phase: value at (c = head-col, t = token) with 16B-chunk XOR swizzle
#pragma unroll
      for (int fa = 0; fa < 4; ++fa) {
#pragma unroll
        for (int fb = 0; fb < 4; ++fb) {
          const int cc = wn * 64 + fb * 16 + li;
#pragma unroll
          for (int r = 0; r < 4; ++r) {
            const int tt = wm * 64 + fa * 16 + lq * 4 + r;
            const int slot = cc * 16 + ((tt >> 3) ^ (cc & 15));
            smem[slot * 8 + (tt & 7)] = f2bf(acc[fa][fb][r]);
          }
        }
      }
      __syncthreads();
      // read phase: 16 lanes cover one c-row's 16 chunks -> 256B coalesced stores
      const int ch = tid & 15;
#pragma unroll
      for (int j = 0; j < 8; ++j) {
        const int cc = (tid >> 4) + 16 * j;
        const uint4 v = *reinterpret_cast<const uint4*>(
            smem + (size_t)(cc * 16 + (ch ^ (cc & 15))) * 8);
        const int bh = b * NHEAD + h0 + (cc >> 6);
        const int d = cc & 63;
        *reinterpret_cast<uint4*>(vT + (size_t)bh * HS * NT + (size_t)d * NT + t0r + ch * 8) = v;
      }
    } else {
      unsigned short* Cb = (unsigned short*)Cout;
#pragma unroll
      for (int fa = 0; fa < 4; ++fa) {
        const int gr = row0 + wm * 64 + fa * 16 + lq * 4;
#pragma unroll
        for (int fb = 0; fb < 4; ++fb) {
          const int gc = col0 + wn * 64 + fb * 16 + li;
#pragma unroll
          for (int r = 0; r < 4; ++r)
            Cb[(size_t)(gr + r) * ldc + gc] = f2bf(acc[fa][fb][r]);
        }
      }
    }
  } else {
    float* Cf = (float*)Cout;
#pragma unroll
    for (int fa = 0; fa < 4; ++fa) {
      const int gr = row0 + wm * 64 + fa * 16 + lq * 4;
#pragma unroll
      for (int fb = 0; fb < 4; ++fb) {
        const int gc = col0 + wn * 64 + fb * 16 + li;
#pragma unroll
        for (int r = 0; r < 4; ++r)
          Cf[(size_t)(gr + r) * ldc + gc] = acc[fa][fb][r];
      }
    }
  }
}

// ---------------- Flash attention: exact-33 LPT halves, dual slot stores ----------------
// (R10 structure — measured 79 us; R12's explicit pairing regressed and is reverted.)
// Total tile-work = 24 heads x 1056 = 25344 = 768 CU-slots x 33 EXACTLY.
// Every q-tile qi (ntile = 2qi+2) splits into two equal halves of qi+1 tiles:
//   part0 = tiles [qi+1, 2qi+2)  (diagonal half) -> slot A (OpartA/laccA)
//   part1 = tiles [0,    qi+1)   (no-mask half)  -> slot B (d_out scratch/laccB)
// 1536 items dispatched strictly descending in size (LPT): round 1 = sizes
// 17..32 (exactly 768 blocks), round 2 = sizes 1..16 (768). Greedy slot
// assignment pairs s with 33-s -> every CU carries ~33 tiles; the scheduler's
// two-round interleave also staggers blocks in time (lost in R12's lockstep).
// Slot B storage = d_out (dead until gemm2, which runs after finalize).
// No atomics, no memset: every slot row written exactly once.
// Inner loop: 3-deep LDS ring, counted vmcnt(4), one s_barrier/tile, swapped
// 32x32 QK^T (zero-C first MFMA), compile-time-split causal mask, v_perm
// packing, permlane P rebuild, l row-sums on the MFMA pipe.
// qkv buffer is [B][T][2C] (Q,K only; V lives in vTb).

__global__ __launch_bounds__(256) void attn(
    const unsigned short* __restrict__ qkv,   // [B][T][2C]
    const unsigned short* __restrict__ vT,    // [B*NH][HS][T]
    float* __restrict__ OpartA,               // [MTOK][NC] fp32 slot A
    float* __restrict__ OpartB,               // [MTOK][NC] fp32 slot B (= d_out scratch)
    float* __restrict__ laccA,                // [B*NH][NT]  fp32 slot A
    float* __restrict__ laccB) {              // [B*NH][NT]  fp32 slot B
  __shared__ unsigned short Ks[3][64 * 64];
  __shared__ unsigned short Vts[3][64 * 64];

  const int tid = threadIdx.x;
  const int wave = tid >> 6;
  const int lane = tid & 63;
  const int l31 = lane & 31;
  const int lh = lane >> 5;
  const int sw = l31 & 7;                     // XOR-swizzle key for frag reads

  // ---- work decode: 1536 = 8 XCD * 3 groups * 64 ranks (descending size) ----
  const int bid = (int)blockIdx.x;
  const int xcd = bid & 7;
  const int wl = bid >> 3;                    // 0..191
  const int grp = xcd * 3 + wl % 3;           // b*12+h
  const int rank = wl / 3;                    // 0..63, size-descending
  const int qi = 31 - (rank >> 1);
  const int part = rank & 1;                  // 0 = diagonal half, 1 = lower half
  const int nt = 2 * qi + 2;
  const int tauS = part ? 0 : (qi + 1);
  const int tauE = part ? (qi + 1) : nt;
  const int b = grp / 12;
  const int h = grp - b * 12;
  const int q0 = qi * 128;
  const int bh = grp;

  const size_t baseQ = (size_t)b * NT * CQK + (size_t)h * HS;
  const size_t baseK = baseQ + NC;
  const unsigned short* kq = qkv + baseK;
  const unsigned short* vbase = vT + (size_t)bh * HS * NT;

  const int qw = q0 + wave * 32;              // wave's first q row
  const int qtok = qw + l31;                  // this lane's q token

  // Q B-fragments (pre-scaled via waT): lane holds Q[q=qw+l31][ks*16+lh*8..+7]
  bf16x8 bq[4];
#pragma unroll
  for (int ks = 0; ks < 4; ++ks)
    bq[ks] = *reinterpret_cast<const bf16x8*>(
        qkv + baseQ + (size_t)(qw + l31) * CQK + ks * 16 + lh * 8);

  // all-ones B fragment for l row-sums on the MFMA pipe
  bf16x8 vones;
#pragma unroll
  for (int i = 0; i < 8; ++i) vones[i] = (__bf16)1.0f;

  f32x16 o0 = {}, o1 = {}, la = {};
  const f32x16 zf = {};            // persistent zero C-operand (LICM'd movs)

  // ---- gload staging geometry: per wave, 2 calls x 8 rows for K and V ----
  // DMA writes linear (wave-uniform LDS base + lane*16B); the XOR swizzle is
  // applied on the per-lane GLOBAL address instead: LDS[R][c] = G[R][c^(R&7)].
  const int grow = lane >> 3;               // row within 8-row group
  const int gch = (lane & 7) ^ grow;        // pre-swizzled 16B chunk
  const int wr0 = wave * 8;                 // uniform row bases
  const int wr1 = wave * 8 + 32;

#define STAGE(TAU, BUFI)                                                        \
  do {                                                                          \
    const int t0s_ = (TAU) * 64;                                                \
    gload_lds16(kq + (size_t)(t0s_ + wr0 + grow) * CQK + gch * 8,               \
                &Ks[BUFI][wr0 * 64]);                                           \
    gload_lds16(kq + (size_t)(t0s_ + wr1 + grow) * CQK + gch * 8,               \
                &Ks[BUFI][wr1 * 64]);                                           \
    gload_lds16(vbase + (size_t)(wr0 + grow) * NT + t0s_ + gch * 8,             \
                &Vts[BUFI][wr0 * 64]);                                          \
    gload_lds16(vbase + (size_t)(wr1 + grow) * NT + t0s_ + gch * 8,             \
                &Vts[BUFI][wr1 * 64]);                                          \
  } while (0)

// exp + pack + permlane-swap one 32-k block (16 S^T regs) into pa[2*KBLK+s].
// DOMASK is a LITERAL 0/1 (selected by a wave-uniform branch at the call site).
#define EXP_PACK(ST, KBLK, DOMASK)                                             \
  do {                                                                         \
    const int kb_ = t0 + (KBLK) * 32 + 4 * lh;                                 \
    float p_[16];                                                              \
    _Pragma("unroll") for (int r = 0; r < 16; ++r) {                           \
      float v_ = (ST)[r];                                                      \
      if (DOMASK) {                                                            \
        const int kt_ = kb_ + (r & 3) + 8 * (r >> 2);                          \
        if (kt_ > qtok) v_ = -INFINITY;                                        \
      }                                                                        \
      p_[r] = __builtin_amdgcn_exp2f(v_);                                      \
    }                                                                          \
    _Pragma("unroll") for (int s = 0; s < 2; ++s) {                            \
      uint32_t a_ = pack_bf2(p_[8 * s + 0], p_[8 * s + 1]);                    \
      uint32_t b_ = pack_bf2(p_[8 * s + 2], p_[8 * s + 3]);                    \
      uint32_t c_ = pack_bf2(p_[8 * s + 4], p_[8 * s + 5]);                    \
      uint32_t d_ = pack_bf2(p_[8 * s + 6], p_[8 * s + 7]);                    \
      asm("v_permlane32_swap_b32 %0, %1" : "+v"(a_), "+v"(c_));                \
      asm("v_permlane32_swap_b32 %0, %1" : "+v"(b_), "+v"(d_));                \
      union { uint32_t u[4]; bf16x8 v8; } pu_;                                 \
      pu_.u[0] = a_; pu_.u[1] = b_; pu_.u[2] = c_; pu_.u[3] = d_;              \
      pa[2 * (KBLK) + s] = pu_.v8;                                             \
    }                                                                          \
  } while (0)

// one PV k-step (16 k-tokens): l += P.1 ; O += P V  (V B-frag rows = d)
#define PV_STEP(KS)                                                            \
  do {                                                                         \
    const int off_ = ((((KS) * 2 + lh) ^ sw) << 3);                            \
    const bf16x8 bv0_ =                                                        \
        *reinterpret_cast<const bf16x8*>(Vc + (size_t)l31 * 64 + off_);        \
    const bf16x8 bv1_ =                                                        \
        *reinterpret_cast<const bf16x8*>(Vc + (size_t)(32 + l31) * 64 + off_); \
    la = mfma32(pa[KS], vones, la);                                            \
    o0 = mfma32(pa[KS], bv0_, o0);                                             \
    o1 = mfma32(pa[KS], bv1_, o1);                                             \
  } while (0)

  // prologue: 2 tiles in flight (single-tile items stage one extra tile; the
  // staged index never exceeds 63, so reads stay in-bounds)
  STAGE(tauS, 0);
  STAGE(tauS + 1, 1);

  int cur = 0;
  for (int tau = tauS; tau < tauE; ++tau) {
    const int t0 = tau * 64;
    // counted drain: tile tau's 4 loads landed; tau+1's stay in flight.
    if (tau + 1 < tauE) asm volatile("s_waitcnt vmcnt(4)" ::: "memory");
    else                asm volatile("s_waitcnt vmcnt(0)" ::: "memory");
    __builtin_amdgcn_s_barrier();          // publish buf[cur] to all waves
    __builtin_amdgcn_sched_barrier(0);     // no hoisting across the barrier
    if (tau + 2 < tauE) {
      int nb = cur + 2; if (nb >= 3) nb -= 3;   // overwrites buf read at tau-1
      STAGE(tau + 2, nb);
    }

    const unsigned short* Kc = Ks[cur];
    const unsigned short* Vc = Vts[cur];

    if (t0 <= qw + 31) {                 // wave has live q-rows in this tile
      const bool act1 = (t0 + 32 <= qw + 31);   // k-block 1 live?
      const bool m0 = (t0 + 31 > qw);           // k-block 0 needs masking?
      const bool m1 = (t0 + 63 > qw);           // k-block 1 needs masking?

      // ---- S^T = K Q^T: A = K rows (k-tokens), B = Q cols ----
      f32x16 st0, st1;
      __builtin_amdgcn_s_setprio(1);
      {
        const bf16x8 ka0 = *reinterpret_cast<const bf16x8*>(
            Kc + (size_t)l31 * 64 + ((lh ^ sw) << 3));
        st0 = mfma32(ka0, bq[0], zf);
      }
#pragma unroll
      for (int ks = 1; ks < 4; ++ks) {
        const bf16x8 ka = *reinterpret_cast<const bf16x8*>(
            Kc + (size_t)l31 * 64 + (((ks * 2 + lh) ^ sw) << 3));
        st0 = mfma32(ka, bq[ks], st0);
      }
      if (act1) {
        {
          const bf16x8 ka0 = *reinterpret_cast<const bf16x8*>(
              Kc + (size_t)(32 + l31) * 64 + ((lh ^ sw) << 3));
          st1 = mfma32(ka0, bq[0], zf);
        }
#pragma unroll
        for (int ks = 1; ks < 4; ++ks) {
          const bf16x8 ka = *reinterpret_cast<const bf16x8*>(
              Kc + (size_t)(32 + l31) * 64 + (((ks * 2 + lh) ^ sw) << 3));
          st1 = mfma32(ka, bq[ks], st1);
        }
      }
      __builtin_amdgcn_s_setprio(0);

      // ---- exp + pack + swap -> pa[4]; mask code only on diagonal tiles ----
      bf16x8 pa[4];
      if (m0) EXP_PACK(st0, 0, 1); else EXP_PACK(st0, 0, 0);
      if (act1) {
        if (m1) EXP_PACK(st1, 1, 1); else EXP_PACK(st1, 1, 0);
      }

      // ---- O += P V ; l += P . ones (MFMA pipe) ----
      __builtin_amdgcn_s_setprio(1);
      PV_STEP(0); PV_STEP(1);
      if (act1) { PV_STEP(2); PV_STEP(3); }
      __builtin_amdgcn_s_setprio(0);
    }
    ++cur; if (cur == 3) cur = 0;
  }
#undef STAGE
#undef EXP_PACK
#undef PV_STEP

  // ---- epilogue: deterministic slot store (no atomics) ----
  // o0/o1 C-layout: col = l31 (d), reg r -> q = qw + (r&3)+8*(r>>2)+4*lh.
  // la[r] = row-sum, uniform across l31.
  float* slotO = part ? OpartB : OpartA;
  float* lrow = (part ? laccB : laccA) + (size_t)bh * NT;
#pragma unroll
  for (int r = 0; r < 16; ++r) {
    const int q = qw + (r & 3) + 8 * (r >> 2) + 4 * lh;
    if (l31 == 0) lrow[q] = la[r];
    float* orow = slotO + ((size_t)b * NT + q) * NC + h * HS;
    orow[l31] = o0[r];
    orow[32 + l31] = o1[r];
  }
}

// ---------------- finalize: merge slots, aob = bf16((OA+OB)/(lA+lB)), all rows ----
__global__ __launch_bounds__(256) void finalize(
    const float* __restrict__ OpartA, const float* __restrict__ OpartB,
    const float* __restrict__ laccA, const float* __restrict__ laccB,
    unsigned short* __restrict__ aob) {
  const int idx4 = (blockIdx.x * 256 + threadIdx.x);
  if (idx4 >= MTOK * NC / 4) return;
  const int idx = idx4 * 4;
  const int row = idx / NC;           // b*NT + t
  const int cc = idx - row * NC;
  const int b = row >> 12;            // NT = 4096
  const int t = row & (NT - 1);
  const int h = cc >> 6;
  const size_t lofs = (size_t)(b * NHEAD + h) * NT + t;
  const float inv = 1.0f / (laccA[lofs] + laccB[lofs]);
  const float4 v0 = *reinterpret_cast<const float4*>(OpartA + (size_t)idx);
  const float4 v1 = *reinterpret_cast<const float4*>(OpartB + (size_t)idx);
  ushort4 o;
  o.x = bft((v0.x + v1.x) * inv); o.y = bft((v0.y + v1.y) * inv);
  o.z = bft((v0.z + v1.z) * inv); o.w = bft((v0.w + v1.w) * inv);
  reinterpret_cast<ushort4*>(aob)[idx4] = o;
}

// ---------------- launch ----------------
extern "C" void kernel_launch(void* const* d_in, const int* in_sizes, int n_in,
                              void* d_out, int out_size, void* d_ws, size_t ws_size,
                              hipStream_t stream) {
  const float* x = (const float*)d_in[0];       // [B,T,C]
  const float* w_attn = (const float*)d_in[1];  // [C, 3C]
  const float* w_proj = (const float*)d_in[2];  // [C, C]
  float* outp = (float*)d_out;

  // ws layout (total ~77.5 MB, safely below the ~89.6 MB proven budget):
  //   OpartA [MTOK][NC] f32  (aliases xb/waT, which die after gemm1)
  //   laccA  [B*NH][NT] f32
  //   laccB  [B*NH][NT] f32
  //   qkvb   [MTOK][2NC] bf16  (Q,K only — V written straight to vTb)
  //   aob    [MTOK][NC] bf16
  //   vTb    [B*NH][HS][T] bf16
  //   wpT    [NC][NC] bf16
  // OpartB = d_out scratch (dead until gemm2, which runs after finalize).
  char* w = (char*)d_ws;
  float* OpartA = (float*)w;
  unsigned short* xb = (unsigned short*)w;                       // aliases OpartA (pre-attn)
  unsigned short* waT = xb + (size_t)MTOK * NC;                  // aliases OpartA tail
  float* laccA = OpartA + (size_t)MTOK * NC;
  float* laccB = laccA + (size_t)NB * NHEAD * NT;
  unsigned short* qkvb = (unsigned short*)(laccB + (size_t)NB * NHEAD * NT);
  unsigned short* aob  = qkvb + (size_t)MTOK * CQK;              // [MTOK][NC] bf16
  unsigned short* vTb  = aob + (size_t)MTOK * NC;                // [B*NH][HS][T]
  unsigned short* wpT  = vTb + (size_t)MTOK * NC;                // [NC][NC] bf16

  // prep: 576 transpose tiles + x-cast blocks
  prep<<<576 + MTOK * NC / 4 / 256, 256, 0, stream>>>(x, w_attn, w_proj, xb, waT, wpT);

  // qkv = x @ w_attn (Q rows of waT pre-scaled); V blocks write vTb directly;
  // Q/K rows land in qkvb at stride 2NC. 1152 = 8*144 blocks, XCD-chunked.
  gemm128<1><<<1152, 256, 0, stream>>>(
      xb, waT, qkvb, vTb, MTOK, C3, NC, CQK, C3 / 128);

  // attention: 1536 exact-LPT half-items, dual deterministic slots (no atomics)
  attn<<<1536, 256, 0, stream>>>(qkvb, vTb, OpartA, outp, laccA, laccB);

  // merge slots + normalize all rows -> bf16 aob
  finalize<<<(MTOK * NC / 4 + 255) / 256, 256, 0, stream>>>(OpartA, outp, laccA, laccB, aob);

  // out = att_out @ w_proj -> fp32 d_out. 384 = 8*48 blocks, XCD-chunked.
  gemm128<0><<<384, 256, 0, stream>>>(
      aob, wpT, outp, nullptr, MTOK, NC, NC, NC, NC / 128);
}